// Round 3
// baseline (826.217 us; speedup 1.0000x reference)
//
#include <hip/hip_runtime.h>
#include <hip/hip_bf16.h>
#include <math.h>

typedef unsigned short u16;
typedef unsigned int u32;
typedef __attribute__((ext_vector_type(8))) __bf16 bf16x8;
typedef __attribute__((ext_vector_type(4))) float f32x4;

#define NNODES 50000
#define NEDGES 800000

__device__ __forceinline__ float bf2f(u16 u) {
    union { u32 i; float f; } v; v.i = ((u32)u) << 16; return v.f;
}
__device__ __forceinline__ u16 f2bf(float x) {
    union { float f; u32 i; } v; v.f = x;
    u32 r = v.i + 0x7fffu + ((v.i >> 16) & 1u);
    return (u16)(r >> 16);
}
__device__ __forceinline__ float lrelu(float x) { return x >= 0.f ? x : 0.2f * x; }

// ---------------- CSR build ----------------
__global__ __launch_bounds__(256) void k_zero(int* a, int count) {
    int i = blockIdx.x * 256 + threadIdx.x;
    if (i < count) a[i] = 0;
}

__global__ __launch_bounds__(256) void k_count(const int* __restrict__ dst, int* __restrict__ counts, int e) {
    int i = blockIdx.x * 256 + threadIdx.x;
    if (i < e) atomicAdd(&counts[dst[i]], 1);
}

__global__ __launch_bounds__(256) void k_scan1(const int* __restrict__ counts, int* __restrict__ row_ptr,
                                               int* __restrict__ bsums, int n) {
    __shared__ int tmp[256];
    int t = threadIdx.x, i = blockIdx.x * 256 + t;
    int v = (i < n) ? counts[i] : 0;
    tmp[t] = v; __syncthreads();
    for (int off = 1; off < 256; off <<= 1) {
        int x = 0; if (t >= off) x = tmp[t - off];
        __syncthreads(); tmp[t] += x; __syncthreads();
    }
    if (i < n) row_ptr[i] = tmp[t] - v;   // exclusive within block
    if (t == 255) bsums[blockIdx.x] = tmp[255];
}

__global__ __launch_bounds__(256) void k_scan2(int* bsums, int nb) {
    __shared__ int tmp[256];
    int t = threadIdx.x;
    int v = (t < nb) ? bsums[t] : 0;
    tmp[t] = v; __syncthreads();
    for (int off = 1; off < 256; off <<= 1) {
        int x = 0; if (t >= off) x = tmp[t - off];
        __syncthreads(); tmp[t] += x; __syncthreads();
    }
    if (t < nb) bsums[t] = tmp[t] - v;    // exclusive
}

__global__ __launch_bounds__(256) void k_scan3(int* __restrict__ row_ptr, const int* __restrict__ bsums,
                                               int n, int total) {
    int i = blockIdx.x * 256 + threadIdx.x;
    if (i < n) row_ptr[i] += bsums[blockIdx.x];
    if (i == 0) row_ptr[n] = total;
}

__global__ __launch_bounds__(256) void k_fill(const int* __restrict__ src, const int* __restrict__ dst,
                                              const int* __restrict__ row_ptr, int* __restrict__ cursor,
                                              int* __restrict__ esrc, int e) {
    int i = blockIdx.x * 256 + threadIdx.x;
    if (i < e) {
        int d = dst[i];
        int p = row_ptr[d] + atomicAdd(&cursor[d], 1);
        esrc[p] = src[i];
    }
}

// ---------------- weight transpose+cast f32[K,N] -> bf16[N,K] ----------------
__global__ __launch_bounds__(256) void k_transpose(const float* __restrict__ W, u16* __restrict__ Wt, int K, int Nn) {
    int i = blockIdx.x * 256 + threadIdx.x;
    if (i < K * Nn) { int k = i / Nn, n = i % Nn; Wt[n * K + k] = f2bf(W[i]); }
}

// ---------------- MFMA bf16 GEMM (bf16 A): C[M,Nn] = A[M,K] * Bt[Nn,K]^T ----------------
// one wave per block; wave computes 16 rows x (16*NT) cols.
// layouts (HW-verified gfx950): A-frag m=lane&15, k=quad*8+j ; B-frag n=lane&15, k=quad*8+j ;
// D col=lane&15, row=quad*4+reg.
template <int NT>
__global__ __launch_bounds__(64) void k_gemm(const u16* __restrict__ A, const u16* __restrict__ Bt,
                                             u16* __restrict__ C, int M, int Nn, int K) {
    int row0 = blockIdx.x * 16;
    int col0 = blockIdx.y * (16 * NT);
    int lane = threadIdx.x;
    int m = lane & 15, quad = lane >> 4;
    f32x4 acc[NT];
#pragma unroll
    for (int t = 0; t < NT; t++)
#pragma unroll
        for (int r = 0; r < 4; r++) acc[t][r] = 0.f;

    const u16* arow = A + (size_t)(row0 + m) * K + quad * 8;
    int full = K >> 5;                     // K multiple of 32 here
    for (int s = 0; s < full; ++s) {
        bf16x8 a = *(const bf16x8*)(arow + s * 32);
#pragma unroll
        for (int t = 0; t < NT; t++) {
            bf16x8 b = *(const bf16x8*)(Bt + (size_t)(col0 + t * 16 + m) * K + s * 32 + quad * 8);
            acc[t] = __builtin_amdgcn_mfma_f32_16x16x32_bf16(a, b, acc[t], 0, 0, 0);
        }
    }
#pragma unroll
    for (int t = 0; t < NT; t++)
#pragma unroll
        for (int r = 0; r < 4; r++) {
            int row = row0 + quad * 4 + r;
            int col = col0 + t * 16 + m;
            if (row < M) C[(size_t)row * Nn + col] = f2bf(acc[t][r]);
        }
}

// ---------------- MFMA GEMM with f32 A input (layer 1): converts A to bf16 in-register ----------------
template <int NT>
__global__ __launch_bounds__(64) void k_gemm_f32a(const float* __restrict__ A, const u16* __restrict__ Bt,
                                                  u16* __restrict__ C, int M, int Nn, int K) {
    int row0 = blockIdx.x * 16;
    int col0 = blockIdx.y * (16 * NT);
    int lane = threadIdx.x;
    int m = lane & 15, quad = lane >> 4;
    f32x4 acc[NT];
#pragma unroll
    for (int t = 0; t < NT; t++)
#pragma unroll
        for (int r = 0; r < 4; r++) acc[t][r] = 0.f;

    const float* arow = A + (size_t)(row0 + m) * K + quad * 8;
    int full = K >> 5, tail = K & 31;   // tail multiple of 8 (K=1000 -> 8)
    for (int s = 0; s < full; ++s) {
        f32x4 a0 = *(const f32x4*)(arow + s * 32);
        f32x4 a1 = *(const f32x4*)(arow + s * 32 + 4);
        bf16x8 a;
#pragma unroll
        for (int j = 0; j < 4; j++) { a[j] = (__bf16)a0[j]; a[4 + j] = (__bf16)a1[j]; }
#pragma unroll
        for (int t = 0; t < NT; t++) {
            bf16x8 b = *(const bf16x8*)(Bt + (size_t)(col0 + t * 16 + m) * K + s * 32 + quad * 8);
            acc[t] = __builtin_amdgcn_mfma_f32_16x16x32_bf16(a, b, acc[t], 0, 0, 0);
        }
    }
    if (tail) {
        int k0 = full * 32;
        bf16x8 a;
#pragma unroll
        for (int j = 0; j < 8; j++) a[j] = (__bf16)0.f;
        if (quad * 8 < tail) {
            f32x4 a0 = *(const f32x4*)(arow + k0);
            f32x4 a1 = *(const f32x4*)(arow + k0 + 4);
#pragma unroll
            for (int j = 0; j < 4; j++) { a[j] = (__bf16)a0[j]; a[4 + j] = (__bf16)a1[j]; }
        }
#pragma unroll
        for (int t = 0; t < NT; t++) {
            bf16x8 b;
#pragma unroll
            for (int j = 0; j < 8; j++) b[j] = (__bf16)0.f;
            if (quad * 8 < tail) b = *(const bf16x8*)(Bt + (size_t)(col0 + t * 16 + m) * K + k0 + quad * 8);
            acc[t] = __builtin_amdgcn_mfma_f32_16x16x32_bf16(a, b, acc[t], 0, 0, 0);
        }
    }
#pragma unroll
    for (int t = 0; t < NT; t++)
#pragma unroll
        for (int r = 0; r < 4; r++) {
            int row = row0 + quad * 4 + r;
            int col = col0 + t * 16 + m;
            if (row < M) C[(size_t)row * Nn + col] = f2bf(acc[t][r]);
        }
}

// ---------------- el/er projections (feat bf16, attn vectors f32) ----------------
__global__ __launch_bounds__(256) void k_eler1(const u16* __restrict__ feat, const float* __restrict__ al,
                                               const float* __restrict__ ar, float* __restrict__ el,
                                               float* __restrict__ er, int n) {
    int node = blockIdx.x * 4 + (threadIdx.x >> 6);
    if (node >= n) return;
    int lane = threadIdx.x & 63;
    const u16* fr = feat + (size_t)node * 128;
    float f0 = bf2f(fr[lane]), f1 = bf2f(fr[64 + lane]);
    float pe = f0 * al[lane] + f1 * al[64 + lane];
    float pr = f0 * ar[lane] + f1 * ar[64 + lane];
#pragma unroll
    for (int off = 32; off; off >>= 1) { pe += __shfl_xor(pe, off); pr += __shfl_xor(pr, off); }
    if (lane == 0) { el[node] = pe; er[node] = pr; }
}

__global__ __launch_bounds__(256) void k_eler2(const u16* __restrict__ feat, const float* __restrict__ al,
                                               const float* __restrict__ ar, float* __restrict__ el,
                                               float* __restrict__ er, int n) {
    int node = blockIdx.x * 4 + (threadIdx.x >> 6);
    if (node >= n) return;
    int lane = threadIdx.x & 63;
    const u16* fr = feat + (size_t)node * 256;
#pragma unroll
    for (int h = 0; h < 2; ++h) {
        float f0 = bf2f(fr[h * 128 + lane]), f1 = bf2f(fr[h * 128 + 64 + lane]);
        float pe = f0 * al[h * 128 + lane] + f1 * al[h * 128 + 64 + lane];
        float pr = f0 * ar[h * 128 + lane] + f1 * ar[h * 128 + 64 + lane];
#pragma unroll
        for (int off = 32; off; off >>= 1) { pe += __shfl_xor(pe, off); pr += __shfl_xor(pr, off); }
        if (lane == 0) { el[node * 2 + h] = pe; er[node * 2 + h] = pr; }
    }
}

__global__ __launch_bounds__(256) void k_elermv(const u16* __restrict__ featm, const u16* __restrict__ featv,
                                                const float* __restrict__ alm, const float* __restrict__ arm,
                                                const float* __restrict__ alv, const float* __restrict__ arv,
                                                float* __restrict__ elm, float* __restrict__ erm,
                                                float* __restrict__ elv, float* __restrict__ erv, int n) {
    int node = blockIdx.x * 4 + (threadIdx.x >> 6);
    if (node >= n) return;
    int lane = threadIdx.x & 63;
    int tbl = lane >> 5, j = lane & 31;
    const u16* ft = tbl ? featv : featm;
    const float* al = tbl ? alv : alm;
    const float* ar = tbl ? arv : arm;
    float f = bf2f(ft[(size_t)node * 32 + j]);
    float pe = f * al[j], pr = f * ar[j];
#pragma unroll
    for (int off = 1; off < 16; off <<= 1) { pe += __shfl_xor(pe, off); pr += __shfl_xor(pr, off); }
    if ((lane & 15) == 0) {
        int h = (lane >> 4) & 1;
        float* el = tbl ? elv : elm; float* er = tbl ? erv : erm;
        el[node * 2 + h] = pe; er[node * 2 + h] = pr;
    }
}

// ---------------- aggregation: layer 1 (H=1,F=128) ----------------
__global__ __launch_bounds__(256) void k_agg1(const int* __restrict__ row_ptr, const int* __restrict__ esrc,
                                              const u16* __restrict__ feat, const float* __restrict__ el,
                                              const float* __restrict__ er, const float* __restrict__ bias,
                                              u16* __restrict__ o_bf, int n) {
    int node = blockIdx.x * 4 + (threadIdx.x >> 6);
    if (node >= n) return;
    int lane = threadIdx.x & 63;
    int beg = row_ptr[node], end = row_ptr[node + 1];
    float erd = er[node];
    float mx = -3.0e38f;
    for (int i = beg + lane; i < end; i += 64) mx = fmaxf(mx, el[esrc[i]]);
#pragma unroll
    for (int off = 32; off; off >>= 1) mx = fmaxf(mx, __shfl_xor(mx, off));
    float me = (end > beg) ? lrelu(mx + erd) : 0.f;  // segment max (lrelu monotonic)
    float acc0 = 0.f, acc1 = 0.f, den = 0.f;
    for (int base = beg; base < end; base += 64) {
        int i = base + lane;
        float w = 0.f; int s = 0;
        if (i < end) { s = esrc[i]; w = expf(lrelu(el[s] + erd) - me); }
        den += w;
        int cnt = min(64, end - base);
        for (int j = 0; j < cnt; ++j) {
            float wj = __shfl(w, j);
            int sj = __shfl(s, j);
            const u32* fp = (const u32*)(feat + (size_t)sj * 128);
            u32 pv = fp[lane];
            acc0 += wj * bf2f((u16)(pv & 0xffff));
            acc1 += wj * bf2f((u16)(pv >> 16));
        }
    }
#pragma unroll
    for (int off = 32; off; off >>= 1) den += __shfl_xor(den, off);
    float inv = (den > 0.f) ? 1.f / den : 0.f;
    float o0 = acc0 * inv + bias[2 * lane];
    float o1 = acc1 * inv + bias[2 * lane + 1];
    u32 pv = (u32)f2bf(o0) | ((u32)f2bf(o1) << 16);
    ((u32*)(o_bf + (size_t)node * 128))[lane] = pv;
}

// ---------------- aggregation: layer 2 (H=2,F=128) + head-mean + residual ----------------
__global__ __launch_bounds__(256) void k_agg2(const int* __restrict__ row_ptr, const int* __restrict__ esrc,
                                              const u16* __restrict__ feat, const float* __restrict__ el,
                                              const float* __restrict__ er, const float* __restrict__ bias,
                                              const u16* __restrict__ o_in, u16* __restrict__ o2_bf, int n) {
    int node = blockIdx.x * 4 + (threadIdx.x >> 6);
    if (node >= n) return;
    int lane = threadIdx.x & 63;
    int beg = row_ptr[node], end = row_ptr[node + 1];
    float er0 = er[node * 2], er1 = er[node * 2 + 1];
    float mx0 = -3.0e38f, mx1 = -3.0e38f;
    for (int i = beg + lane; i < end; i += 64) {
        int s = esrc[i];
        mx0 = fmaxf(mx0, el[s * 2]); mx1 = fmaxf(mx1, el[s * 2 + 1]);
    }
#pragma unroll
    for (int off = 32; off; off >>= 1) { mx0 = fmaxf(mx0, __shfl_xor(mx0, off)); mx1 = fmaxf(mx1, __shfl_xor(mx1, off)); }
    float me0 = (end > beg) ? lrelu(mx0 + er0) : 0.f;
    float me1 = (end > beg) ? lrelu(mx1 + er1) : 0.f;
    float a00 = 0.f, a01 = 0.f, a10 = 0.f, a11 = 0.f, d0 = 0.f, d1 = 0.f;
    for (int base = beg; base < end; base += 64) {
        int i = base + lane;
        float w0 = 0.f, w1 = 0.f; int s = 0;
        if (i < end) {
            s = esrc[i];
            w0 = expf(lrelu(el[s * 2] + er0) - me0);
            w1 = expf(lrelu(el[s * 2 + 1] + er1) - me1);
        }
        d0 += w0; d1 += w1;
        int cnt = min(64, end - base);
        for (int j = 0; j < cnt; ++j) {
            float w0j = __shfl(w0, j), w1j = __shfl(w1, j);
            int sj = __shfl(s, j);
            const u32* fp = (const u32*)(feat + (size_t)sj * 256);
            u32 p0 = fp[lane], p1 = fp[64 + lane];
            a00 += w0j * bf2f((u16)(p0 & 0xffff)); a01 += w0j * bf2f((u16)(p0 >> 16));
            a10 += w1j * bf2f((u16)(p1 & 0xffff)); a11 += w1j * bf2f((u16)(p1 >> 16));
        }
    }
#pragma unroll
    for (int off = 32; off; off >>= 1) { d0 += __shfl_xor(d0, off); d1 += __shfl_xor(d1, off); }
    float i0 = (d0 > 0.f) ? 1.f / d0 : 0.f, i1 = (d1 > 0.f) ? 1.f / d1 : 0.f;
    int c = 2 * lane;
    float r0 = bf2f(o_in[(size_t)node * 128 + c]), r1 = bf2f(o_in[(size_t)node * 128 + c + 1]);
    float o0 = 0.5f * ((a00 * i0 + bias[c]) + (a10 * i1 + bias[128 + c])) + r0;
    float o1 = 0.5f * ((a01 * i0 + bias[c + 1]) + (a11 * i1 + bias[128 + c + 1])) + r1;
    u32 pv = (u32)f2bf(o0) | ((u32)f2bf(o1) << 16);
    ((u32*)(o2_bf + (size_t)node * 128))[lane] = pv;
}

// ---------------- aggregation: mean & var fused (H=2,F=16) + reparameterize ----------------
__global__ __launch_bounds__(256) void k_aggmv(const int* __restrict__ row_ptr, const int* __restrict__ esrc,
                                               const u16* __restrict__ featm, const u16* __restrict__ featv,
                                               const float* __restrict__ elm, const float* __restrict__ erm,
                                               const float* __restrict__ elv, const float* __restrict__ erv,
                                               const float* __restrict__ bm, const float* __restrict__ bv,
                                               const float* __restrict__ eps, float* __restrict__ out, int n) {
    int node = blockIdx.x * 4 + (threadIdx.x >> 6);
    if (node >= n) return;
    int lane = threadIdx.x & 63;
    int f = lane & 15, h = (lane >> 4) & 1, tbl = lane >> 5;
    const float* el_t = tbl ? elv : elm;
    const float* er_t = tbl ? erv : erm;
    const u16* ft = tbl ? featv : featm;
    const float* bias_t = tbl ? bv : bm;
    int beg = row_ptr[node], end = row_ptr[node + 1];
    float erd = er_t[node * 2 + h];
    float mx = -3.0e38f;
    for (int i = beg + f; i < end; i += 16) mx = fmaxf(mx, el_t[esrc[i] * 2 + h]);
#pragma unroll
    for (int off = 1; off < 16; off <<= 1) mx = fmaxf(mx, __shfl_xor(mx, off));
    float me = (end > beg) ? lrelu(mx + erd) : 0.f;
    float acc = 0.f, den = 0.f;
    for (int j = beg; j < end; ++j) {
        int s = esrc[j];
        float w = expf(lrelu(el_t[s * 2 + h] + erd) - me);
        den += w;
        acc += w * bf2f(ft[(size_t)s * 32 + h * 16 + f]);
    }
    float inv = (den > 0.f) ? 1.f / den : 0.f;
    float outc = acc * inv + bias_t[h * 16 + f];
    float hm = 0.5f * (outc + __shfl_xor(outc, 16));  // mean over the 2 heads
    float meanv = __shfl(hm, f);                      // mean-table value
    float varp = __shfl(hm, 32 + f);                  // var-table value (pre-exp)
    if (lane < 16) {
        float var = expf(varp);
        float z = meanv + sqrtf(var) * eps[(size_t)node * 16 + f];
        size_t base = (size_t)node * 16 + f;
        out[base] = z;
        out[(size_t)NNODES * 16 + base] = meanv;
        out[(size_t)2 * NNODES * 16 + base] = var;
    }
}

// ---------------- host ----------------
extern "C" void kernel_launch(void* const* d_in, const int* in_sizes, int n_in,
                              void* d_out, int out_size, void* d_ws, size_t ws_size,
                              hipStream_t stream) {
    const int N = NNODES, E = NEDGES;
    const float* x   = (const float*)d_in[0];
    const int* src   = (const int*)d_in[1];
    const int* dst   = (const int*)d_in[2];
    const float* W1  = (const float*)d_in[3];
    const float* al1 = (const float*)d_in[4];
    const float* ar1 = (const float*)d_in[5];
    const float* b1  = (const float*)d_in[6];
    const float* W2  = (const float*)d_in[7];
    const float* al2 = (const float*)d_in[8];
    const float* ar2 = (const float*)d_in[9];
    const float* b2  = (const float*)d_in[10];
    const float* Wm  = (const float*)d_in[11];
    const float* alm = (const float*)d_in[12];
    const float* arm = (const float*)d_in[13];
    const float* bm  = (const float*)d_in[14];
    const float* Wv  = (const float*)d_in[15];
    const float* alv = (const float*)d_in[16];
    const float* arv = (const float*)d_in[17];
    const float* bv  = (const float*)d_in[18];
    const float* eps = (const float*)d_in[19];
    float* out = (float*)d_out;

    // ---- workspace layout with lifetime aliasing (peak ~58 MB) ----
    char* ws = (char*)d_ws;
    size_t off = 0;
    auto take = [&](size_t bytes) { size_t r = off; off += (bytes + 255) & ~(size_t)255; return r; };
    int* counts   = (int*)(ws + take((size_t)N * 4));
    int* cursor   = (int*)(ws + take((size_t)N * 4));
    int* row_ptr  = (int*)(ws + take((size_t)(N + 1) * 4));
    int* bsums    = (int*)(ws + take(256 * 4));
    int* esrc     = (int*)(ws + take((size_t)E * 4));
    u16* W1t      = (u16*)(ws + take((size_t)128 * 1000 * 2));
    u16* W2t      = (u16*)(ws + take((size_t)256 * 128 * 2));
    u16* Wmt      = (u16*)(ws + take((size_t)32 * 128 * 2));
    u16* Wvt      = (u16*)(ws + take((size_t)32 * 128 * 2));
    float* el1    = (float*)(ws + take((size_t)N * 4));
    float* er1    = (float*)(ws + take((size_t)N * 4));
    float* el2    = (float*)(ws + take((size_t)N * 2 * 4));
    float* er2    = (float*)(ws + take((size_t)N * 2 * 4));
    float* elm    = (float*)(ws + take((size_t)N * 2 * 4));
    float* erm    = (float*)(ws + take((size_t)N * 2 * 4));
    float* elv    = (float*)(ws + take((size_t)N * 2 * 4));
    float* erv    = (float*)(ws + take((size_t)N * 2 * 4));
    u16* o_bf     = (u16*)(ws + take((size_t)N * 128 * 2));
    u16* o2_bf    = (u16*)(ws + take((size_t)N * 128 * 2));
    // big region R (25.6 MB), time-multiplexed:
    //   [gemm1..agg1]   feat1 = R[0 .. 12.8MB)
    //   [gemm2..agg2]   feat2 = R[0 .. 25.6MB)
    //   [gemm-mv..end]  featm = R[0 .. 1.6MB), featv = R[+1.6MB)
    u16* R        = (u16*)(ws + take((size_t)N * 256 * 2));
    u16* feat1    = R;
    u16* feat2    = R;
    u16* featm    = R;
    u16* featv    = R + (size_t)N * 32;
    (void)ws_size; (void)n_in; (void)in_sizes; (void)out_size;

    const int nb = (N + 255) / 256;           // 196
    const int eb = (E + 255) / 256;           // 3125
    const int wb = (N + 3) / 4;               // 12500 (4 waves/block, 1 node/wave)

    // CSR build
    k_zero<<<dim3(nb), 256, 0, stream>>>(counts, N);
    k_zero<<<dim3(nb), 256, 0, stream>>>(cursor, N);
    k_count<<<dim3(eb), 256, 0, stream>>>(dst, counts, E);
    k_scan1<<<dim3(nb), 256, 0, stream>>>(counts, row_ptr, bsums, N);
    k_scan2<<<dim3(1), 256, 0, stream>>>(bsums, nb);
    k_scan3<<<dim3(nb), 256, 0, stream>>>(row_ptr, bsums, N, E);
    k_fill<<<dim3(eb), 256, 0, stream>>>(src, dst, row_ptr, cursor, esrc, E);

    // weight transposes (f32 -> bf16)
    k_transpose<<<dim3((1000 * 128 + 255) / 256), 256, 0, stream>>>(W1, W1t, 1000, 128);
    k_transpose<<<dim3((128 * 256 + 255) / 256), 256, 0, stream>>>(W2, W2t, 128, 256);
    k_transpose<<<dim3((128 * 32 + 255) / 256), 256, 0, stream>>>(Wm, Wmt, 128, 32);
    k_transpose<<<dim3((128 * 32 + 255) / 256), 256, 0, stream>>>(Wv, Wvt, 128, 32);

    // layer 1 (A is f32)
    k_gemm_f32a<8><<<dim3(N / 16, 1), 64, 0, stream>>>(x, W1t, feat1, N, 128, 1000);
    k_eler1<<<dim3(wb), 256, 0, stream>>>(feat1, al1, ar1, el1, er1, N);
    k_agg1<<<dim3(wb), 256, 0, stream>>>(row_ptr, esrc, feat1, el1, er1, b1, o_bf, N);

    // layer 2 (feat2 overwrites R; feat1 is dead after k_agg1)
    k_gemm<8><<<dim3(N / 16, 2), 64, 0, stream>>>(o_bf, W2t, feat2, N, 256, 128);
    k_eler2<<<dim3(wb), 256, 0, stream>>>(feat2, al2, ar2, el2, er2, N);
    k_agg2<<<dim3(wb), 256, 0, stream>>>(row_ptr, esrc, feat2, el2, er2, b2, o_bf, o2_bf, N);

    // mean/var layers (featm/featv overwrite R; feat2 is dead after k_agg2)
    k_gemm<2><<<dim3(N / 16, 1), 64, 0, stream>>>(o2_bf, Wmt, featm, N, 32, 128);
    k_gemm<2><<<dim3(N / 16, 1), 64, 0, stream>>>(o2_bf, Wvt, featv, N, 32, 128);
    k_elermv<<<dim3(wb), 256, 0, stream>>>(featm, featv, alm, arm, alv, arv, elm, erm, elv, erv, N);
    k_aggmv<<<dim3(wb), 256, 0, stream>>>(row_ptr, esrc, featm, featv, elm, erm, elv, erv,
                                          bm, bv, eps, out, N);
}

// Round 5
// 679.187 us; speedup vs baseline: 1.2165x; 1.2165x over previous
//
#include <hip/hip_runtime.h>
#include <hip/hip_bf16.h>
#include <math.h>

typedef unsigned short u16;
typedef unsigned int u32;
typedef __attribute__((ext_vector_type(8))) __bf16 bf16x8;
typedef __attribute__((ext_vector_type(4))) float f32x4;
typedef __attribute__((ext_vector_type(4))) u32 u32x4;

#define NNODES 50000
#define NEDGES 800000

__device__ __forceinline__ float bf2f(u16 u) {
    union { u32 i; float f; } v; v.i = ((u32)u) << 16; return v.f;
}
__device__ __forceinline__ u16 f2bf(float x) {
    union { float f; u32 i; } v; v.f = x;
    u32 r = v.i + 0x7fffu + ((v.i >> 16) & 1u);
    return (u16)(r >> 16);
}
__device__ __forceinline__ float lrelu(float x) { return x >= 0.f ? x : 0.2f * x; }

// ---------------- CSR build ----------------
__global__ __launch_bounds__(256) void k_zero(int* a, int count) {
    int i = blockIdx.x * 256 + threadIdx.x;
    if (i < count) a[i] = 0;
}

__global__ __launch_bounds__(256) void k_count(const int* __restrict__ dst, int* __restrict__ counts, int e) {
    int i = blockIdx.x * 256 + threadIdx.x;
    if (i < e) atomicAdd(&counts[dst[i]], 1);
}

__global__ __launch_bounds__(256) void k_scan1(const int* __restrict__ counts, int* __restrict__ row_ptr,
                                               int* __restrict__ bsums, int n) {
    __shared__ int tmp[256];
    int t = threadIdx.x, i = blockIdx.x * 256 + t;
    int v = (i < n) ? counts[i] : 0;
    tmp[t] = v; __syncthreads();
    for (int off = 1; off < 256; off <<= 1) {
        int x = 0; if (t >= off) x = tmp[t - off];
        __syncthreads(); tmp[t] += x; __syncthreads();
    }
    if (i < n) row_ptr[i] = tmp[t] - v;
    if (t == 255) bsums[blockIdx.x] = tmp[255];
}

__global__ __launch_bounds__(256) void k_scan2(int* bsums, int nb) {
    __shared__ int tmp[256];
    int t = threadIdx.x;
    int v = (t < nb) ? bsums[t] : 0;
    tmp[t] = v; __syncthreads();
    for (int off = 1; off < 256; off <<= 1) {
        int x = 0; if (t >= off) x = tmp[t - off];
        __syncthreads(); tmp[t] += x; __syncthreads();
    }
    if (t < nb) bsums[t] = tmp[t] - v;
}

__global__ __launch_bounds__(256) void k_scan3(int* __restrict__ row_ptr, const int* __restrict__ bsums,
                                               int n, int total) {
    int i = blockIdx.x * 256 + threadIdx.x;
    if (i < n) row_ptr[i] += bsums[blockIdx.x];
    if (i == 0) row_ptr[n] = total;
}

__global__ __launch_bounds__(256) void k_fill(const int* __restrict__ src, const int* __restrict__ dst,
                                              const int* __restrict__ row_ptr, int* __restrict__ cursor,
                                              int* __restrict__ esrc, int e) {
    int i = blockIdx.x * 256 + threadIdx.x;
    if (i < e) {
        int d = dst[i];
        int p = row_ptr[d] + atomicAdd(&cursor[d], 1);
        esrc[p] = src[i];
    }
}

// ---------------- weight transpose+cast f32[K,N] -> bf16[N,K] ----------------
__global__ __launch_bounds__(256) void k_transpose(const float* __restrict__ W, u16* __restrict__ Wt, int K, int Nn) {
    int i = blockIdx.x * 256 + threadIdx.x;
    if (i < K * Nn) { int k = i / Nn, n = i % Nn; Wt[n * K + k] = f2bf(W[i]); }
}

// ---------------- A-fragment loaders (f32 or bf16 source) ----------------
__device__ __forceinline__ void load_af(const float* __restrict__ arow, int k0, int K, bf16x8& a) {
    if (k0 + 8 <= K) {
        f32x4 a0 = *(const f32x4*)(arow + k0);
        f32x4 a1 = *(const f32x4*)(arow + k0 + 4);
#pragma unroll
        for (int j = 0; j < 4; j++) { a[j] = (__bf16)a0[j]; a[4 + j] = (__bf16)a1[j]; }
    } else {
#pragma unroll
        for (int j = 0; j < 8; j++) a[j] = (__bf16)0.f;
    }
}
__device__ __forceinline__ void load_af(const u16* __restrict__ arow, int k0, int K, bf16x8& a) {
    if (k0 + 8 <= K) a = *(const bf16x8*)(arow + k0);
    else {
#pragma unroll
        for (int j = 0; j < 8; j++) a[j] = (__bf16)0.f;
    }
}

// ---------------- Tiled MFMA GEMM: C[M,Nn](bf16) = A[M,K] * Bt[Nn,K]^T ----------------
template <typename AT>
__global__ __launch_bounds__(256) void k_gemm_tiled(const AT* __restrict__ A, const u16* __restrict__ Bt,
                                                    u16* __restrict__ C, int M, int Nn, int K) {
    __shared__ __align__(16) u16 lb[2][128 * 40];
    const int tid = threadIdx.x;
    const int wave = tid >> 6, lane = tid & 63;
    const int m = lane & 15, quad = lane >> 4;
    const int row0 = blockIdx.x * 64 + wave * 16;
    const int col0 = blockIdx.y * 128;

    f32x4 acc[8];
#pragma unroll
    for (int t = 0; t < 8; t++)
#pragma unroll
        for (int r = 0; r < 4; r++) acc[t][r] = 0.f;

    int ar = row0 + m; if (ar > M - 1) ar = M - 1;   // clamp OOB rows (stores guarded)
    const AT* arow = A + (size_t)ar * K;
    const int scol = tid & 127;          // staging col
    const int sseg = (tid >> 7) * 16;    // staging k-base within tile (0 or 16)
    const u16* bcol = Bt + (size_t)(col0 + scol) * K;

    const int nsteps = (K + 31) >> 5;

#pragma unroll
    for (int p = 0; p < 2; ++p) {
        int kl = sseg + p * 8;
        u32x4 v = 0;
        if (kl < K) v = *(const u32x4*)(bcol + kl);
        *(u32x4*)&lb[0][scol * 40 + kl] = v;
    }
    bf16x8 acur, anext;
    load_af(arow, quad * 8, K, acur);
    __syncthreads();

    for (int s = 0; s < nsteps; ++s) {
        const int buf = s & 1;
        if (s + 1 < nsteps) {
            const int k0n = (s + 1) * 32;
            load_af(arow, k0n + quad * 8, K, anext);
#pragma unroll
            for (int p = 0; p < 2; ++p) {
                int kl = sseg + p * 8;
                u32x4 v = 0;
                if (k0n + kl < K) v = *(const u32x4*)(bcol + k0n + kl);
                *(u32x4*)&lb[buf ^ 1][scol * 40 + kl] = v;
            }
        }
#pragma unroll
        for (int t = 0; t < 8; ++t) {
            bf16x8 b = *(const bf16x8*)&lb[buf][(t * 16 + m) * 40 + quad * 8];
            acc[t] = __builtin_amdgcn_mfma_f32_16x16x32_bf16(acur, b, acc[t], 0, 0, 0);
        }
        acur = anext;
        __syncthreads();
    }

#pragma unroll
    for (int t = 0; t < 8; t++)
#pragma unroll
        for (int r = 0; r < 4; r++) {
            int row = row0 + quad * 4 + r;
            int col = col0 + t * 16 + m;
            if (row < M) C[(size_t)row * Nn + col] = f2bf(acc[t][r]);
        }
}

// ---------------- small MFMA GEMM (bf16 A), one wave/block: N=32 mean/var ----------------
template <int NT>
__global__ __launch_bounds__(64) void k_gemm(const u16* __restrict__ A, const u16* __restrict__ Bt,
                                             u16* __restrict__ C, int M, int Nn, int K) {
    int row0 = blockIdx.x * 16;
    int col0 = blockIdx.y * (16 * NT);
    int lane = threadIdx.x;
    int m = lane & 15, quad = lane >> 4;
    f32x4 acc[NT];
#pragma unroll
    for (int t = 0; t < NT; t++)
#pragma unroll
        for (int r = 0; r < 4; r++) acc[t][r] = 0.f;

    const u16* arow = A + (size_t)(row0 + m) * K + quad * 8;
    int full = K >> 5;
    for (int s = 0; s < full; ++s) {
        bf16x8 a = *(const bf16x8*)(arow + s * 32);
#pragma unroll
        for (int t = 0; t < NT; t++) {
            bf16x8 b = *(const bf16x8*)(Bt + (size_t)(col0 + t * 16 + m) * K + s * 32 + quad * 8);
            acc[t] = __builtin_amdgcn_mfma_f32_16x16x32_bf16(a, b, acc[t], 0, 0, 0);
        }
    }
#pragma unroll
    for (int t = 0; t < NT; t++)
#pragma unroll
        for (int r = 0; r < 4; r++) {
            int row = row0 + quad * 4 + r;
            int col = col0 + t * 16 + m;
            if (row < M) C[(size_t)row * Nn + col] = f2bf(acc[t][r]);
        }
}

// ---------------- el/er projections ----------------
__global__ __launch_bounds__(256) void k_eler1(const u16* __restrict__ feat, const float* __restrict__ al,
                                               const float* __restrict__ ar, float* __restrict__ el,
                                               float* __restrict__ er, int n) {
    int node = blockIdx.x * 4 + (threadIdx.x >> 6);
    if (node >= n) return;
    int lane = threadIdx.x & 63;
    const u16* fr = feat + (size_t)node * 128;
    float f0 = bf2f(fr[lane]), f1 = bf2f(fr[64 + lane]);
    float pe = f0 * al[lane] + f1 * al[64 + lane];
    float pr = f0 * ar[lane] + f1 * ar[64 + lane];
#pragma unroll
    for (int off = 32; off; off >>= 1) { pe += __shfl_xor(pe, off); pr += __shfl_xor(pr, off); }
    if (lane == 0) { el[node] = pe; er[node] = pr; }
}

__global__ __launch_bounds__(256) void k_eler2(const u16* __restrict__ feat, const float* __restrict__ al,
                                               const float* __restrict__ ar, float* __restrict__ el,
                                               float* __restrict__ er, int n) {
    int node = blockIdx.x * 4 + (threadIdx.x >> 6);
    if (node >= n) return;
    int lane = threadIdx.x & 63;
    const u16* fr = feat + (size_t)node * 256;
#pragma unroll
    for (int h = 0; h < 2; ++h) {
        float f0 = bf2f(fr[h * 128 + lane]), f1 = bf2f(fr[h * 128 + 64 + lane]);
        float pe = f0 * al[h * 128 + lane] + f1 * al[h * 128 + 64 + lane];
        float pr = f0 * ar[h * 128 + lane] + f1 * ar[h * 128 + 64 + lane];
#pragma unroll
        for (int off = 32; off; off >>= 1) { pe += __shfl_xor(pe, off); pr += __shfl_xor(pr, off); }
        if (lane == 0) { el[node * 2 + h] = pe; er[node * 2 + h] = pr; }
    }
}

__global__ __launch_bounds__(256) void k_elermv(const u16* __restrict__ featm, const u16* __restrict__ featv,
                                                const float* __restrict__ alm, const float* __restrict__ arm,
                                                const float* __restrict__ alv, const float* __restrict__ arv,
                                                float* __restrict__ elm, float* __restrict__ erm,
                                                float* __restrict__ elv, float* __restrict__ erv, int n) {
    int node = blockIdx.x * 4 + (threadIdx.x >> 6);
    if (node >= n) return;
    int lane = threadIdx.x & 63;
    int tbl = lane >> 5, j = lane & 31;
    const u16* ft = tbl ? featv : featm;
    const float* al = tbl ? alv : alm;
    const float* ar = tbl ? arv : arm;
    float f = bf2f(ft[(size_t)node * 32 + j]);
    float pe = f * al[j], pr = f * ar[j];
#pragma unroll
    for (int off = 1; off < 16; off <<= 1) { pe += __shfl_xor(pe, off); pr += __shfl_xor(pr, off); }
    if ((lane & 15) == 0) {
        int h = (lane >> 4) & 1;
        float* el = tbl ? elv : elm; float* er = tbl ? erv : erm;
        el[node * 2 + h] = pe; er[node * 2 + h] = pr;
    }
}

// ---------------- aggregation: layer 1 (H=1,F=128), 4-wide pipelined gathers ----------------
__global__ __launch_bounds__(256) void k_agg1(const int* __restrict__ row_ptr, const int* __restrict__ esrc,
                                              const u16* __restrict__ feat, const float* __restrict__ el,
                                              const float* __restrict__ er, const float* __restrict__ bias,
                                              u16* __restrict__ o_bf, int n) {
    int node = blockIdx.x * 4 + (threadIdx.x >> 6);
    if (node >= n) return;
    int lane = threadIdx.x & 63;
    int beg = row_ptr[node], end = row_ptr[node + 1];
    float erd = er[node];
    float mx = -3.0e38f;
    for (int i = beg + lane; i < end; i += 64) mx = fmaxf(mx, el[esrc[i]]);
#pragma unroll
    for (int off = 32; off; off >>= 1) mx = fmaxf(mx, __shfl_xor(mx, off));
    float me = (end > beg) ? lrelu(mx + erd) : 0.f;
    float acc0 = 0.f, acc1 = 0.f, den = 0.f;
    for (int base = beg; base < end; base += 64) {
        int i = base + lane;
        float w = 0.f; int s = 0;
        if (i < end) { s = esrc[i]; w = expf(lrelu(el[s] + erd) - me); }
        den += w;
        int cnt = min(64, end - base);
        int j = 0;
        for (; j + 4 <= cnt; j += 4) {
            float w0 = __shfl(w, j), w1 = __shfl(w, j + 1), w2 = __shfl(w, j + 2), w3 = __shfl(w, j + 3);
            int s0 = __shfl(s, j), s1 = __shfl(s, j + 1), s2 = __shfl(s, j + 2), s3 = __shfl(s, j + 3);
            u32 p0 = ((const u32*)(feat + (size_t)s0 * 128))[lane];
            u32 p1 = ((const u32*)(feat + (size_t)s1 * 128))[lane];
            u32 p2 = ((const u32*)(feat + (size_t)s2 * 128))[lane];
            u32 p3 = ((const u32*)(feat + (size_t)s3 * 128))[lane];
            acc0 += w0 * bf2f((u16)(p0 & 0xffff)) + w1 * bf2f((u16)(p1 & 0xffff))
                  + w2 * bf2f((u16)(p2 & 0xffff)) + w3 * bf2f((u16)(p3 & 0xffff));
            acc1 += w0 * bf2f((u16)(p0 >> 16)) + w1 * bf2f((u16)(p1 >> 16))
                  + w2 * bf2f((u16)(p2 >> 16)) + w3 * bf2f((u16)(p3 >> 16));
        }
        for (; j < cnt; ++j) {
            float wj = __shfl(w, j);
            int sj = __shfl(s, j);
            u32 pv = ((const u32*)(feat + (size_t)sj * 128))[lane];
            acc0 += wj * bf2f((u16)(pv & 0xffff));
            acc1 += wj * bf2f((u16)(pv >> 16));
        }
    }
#pragma unroll
    for (int off = 32; off; off >>= 1) den += __shfl_xor(den, off);
    float inv = (den > 0.f) ? 1.f / den : 0.f;
    float o0 = acc0 * inv + bias[2 * lane];
    float o1 = acc1 * inv + bias[2 * lane + 1];
    u32 pv = (u32)f2bf(o0) | ((u32)f2bf(o1) << 16);
    ((u32*)(o_bf + (size_t)node * 128))[lane] = pv;
}

// ---------------- aggregation: layer 2 (H=2,F=128) + head-mean + residual, 2-wide ----------------
__global__ __launch_bounds__(256) void k_agg2(const int* __restrict__ row_ptr, const int* __restrict__ esrc,
                                              const u16* __restrict__ feat, const float* __restrict__ el,
                                              const float* __restrict__ er, const float* __restrict__ bias,
                                              const u16* __restrict__ o_in, u16* __restrict__ o2_bf, int n) {
    int node = blockIdx.x * 4 + (threadIdx.x >> 6);
    if (node >= n) return;
    int lane = threadIdx.x & 63;
    int beg = row_ptr[node], end = row_ptr[node + 1];
    float er0 = er[node * 2], er1 = er[node * 2 + 1];
    float mx0 = -3.0e38f, mx1 = -3.0e38f;
    for (int i = beg + lane; i < end; i += 64) {
        int s = esrc[i];
        float2 e2 = *(const float2*)(el + 2 * s);
        mx0 = fmaxf(mx0, e2.x); mx1 = fmaxf(mx1, e2.y);
    }
#pragma unroll
    for (int off = 32; off; off >>= 1) { mx0 = fmaxf(mx0, __shfl_xor(mx0, off)); mx1 = fmaxf(mx1, __shfl_xor(mx1, off)); }
    float me0 = (end > beg) ? lrelu(mx0 + er0) : 0.f;
    float me1 = (end > beg) ? lrelu(mx1 + er1) : 0.f;
    float a00 = 0.f, a01 = 0.f, a10 = 0.f, a11 = 0.f, d0 = 0.f, d1 = 0.f;
    for (int base = beg; base < end; base += 64) {
        int i = base + lane;
        float w0 = 0.f, w1 = 0.f; int s = 0;
        if (i < end) {
            s = esrc[i];
            float2 e2 = *(const float2*)(el + 2 * s);
            w0 = expf(lrelu(e2.x + er0) - me0);
            w1 = expf(lrelu(e2.y + er1) - me1);
        }
        d0 += w0; d1 += w1;
        int cnt = min(64, end - base);
        int j = 0;
        for (; j + 2 <= cnt; j += 2) {
            float w0a = __shfl(w0, j), w1a = __shfl(w1, j), w0b = __shfl(w0, j + 1), w1b = __shfl(w1, j + 1);
            int sa = __shfl(s, j), sb = __shfl(s, j + 1);
            const u32* fa = (const u32*)(feat + (size_t)sa * 256);
            const u32* fb = (const u32*)(feat + (size_t)sb * 256);
            u32 pa0 = fa[lane], pa1 = fa[64 + lane];
            u32 pb0 = fb[lane], pb1 = fb[64 + lane];
            a00 += w0a * bf2f((u16)(pa0 & 0xffff)) + w0b * bf2f((u16)(pb0 & 0xffff));
            a01 += w0a * bf2f((u16)(pa0 >> 16))    + w0b * bf2f((u16)(pb0 >> 16));
            a10 += w1a * bf2f((u16)(pa1 & 0xffff)) + w1b * bf2f((u16)(pb1 & 0xffff));
            a11 += w1a * bf2f((u16)(pa1 >> 16))    + w1b * bf2f((u16)(pb1 >> 16));
        }
        for (; j < cnt; ++j) {
            float w0j = __shfl(w0, j), w1j = __shfl(w1, j);
            int sj = __shfl(s, j);
            const u32* fp = (const u32*)(feat + (size_t)sj * 256);
            u32 p0 = fp[lane], p1 = fp[64 + lane];
            a00 += w0j * bf2f((u16)(p0 & 0xffff)); a01 += w0j * bf2f((u16)(p0 >> 16));
            a10 += w1j * bf2f((u16)(p1 & 0xffff)); a11 += w1j * bf2f((u16)(p1 >> 16));
        }
    }
#pragma unroll
    for (int off = 32; off; off >>= 1) { d0 += __shfl_xor(d0, off); d1 += __shfl_xor(d1, off); }
    float i0 = (d0 > 0.f) ? 1.f / d0 : 0.f, i1 = (d1 > 0.f) ? 1.f / d1 : 0.f;
    int c = 2 * lane;
    float r0 = bf2f(o_in[(size_t)node * 128 + c]), r1 = bf2f(o_in[(size_t)node * 128 + c + 1]);
    float o0 = 0.5f * ((a00 * i0 + bias[c]) + (a10 * i1 + bias[128 + c])) + r0;
    float o1 = 0.5f * ((a01 * i0 + bias[c + 1]) + (a11 * i1 + bias[128 + c + 1])) + r1;
    u32 pv = (u32)f2bf(o0) | ((u32)f2bf(o1) << 16);
    ((u32*)(o2_bf + (size_t)node * 128))[lane] = pv;
}

// ---------------- aggregation: mean & var fused (H=2,F=16), edge-parallel + reparameterize ----------------
// lane = tbl*32 + h*16 + f. FIX vs round 4: all __shfl broadcasts are UNCONDITIONAL
// (convergent ops must not sit under a lane-divergent ternary); selection of the
// broadcast RESULT by (tbl,h) is a local cndmask and is safe.
__global__ __launch_bounds__(256) void k_aggmv(const int* __restrict__ row_ptr, const int* __restrict__ esrc,
                                               const u16* __restrict__ featm, const u16* __restrict__ featv,
                                               const float* __restrict__ elm, const float* __restrict__ erm,
                                               const float* __restrict__ elv, const float* __restrict__ erv,
                                               const float* __restrict__ bm, const float* __restrict__ bv,
                                               const float* __restrict__ eps, float* __restrict__ out, int n) {
    int node = blockIdx.x * 4 + (threadIdx.x >> 6);
    if (node >= n) return;
    int lane = threadIdx.x & 63;
    int f = lane & 15, h = (lane >> 4) & 1, tbl = lane >> 5;
    int beg = row_ptr[node], end = row_ptr[node + 1];
    float erm0 = erm[2 * node], erm1 = erm[2 * node + 1];
    float erv0 = erv[2 * node], erv1 = erv[2 * node + 1];
    float mm0 = -3.0e38f, mm1 = -3.0e38f, mv0 = -3.0e38f, mv1 = -3.0e38f;
    for (int i = beg + lane; i < end; i += 64) {
        int s = esrc[i];
        float2 em = *(const float2*)(elm + 2 * s);
        float2 ev = *(const float2*)(elv + 2 * s);
        mm0 = fmaxf(mm0, em.x); mm1 = fmaxf(mm1, em.y);
        mv0 = fmaxf(mv0, ev.x); mv1 = fmaxf(mv1, ev.y);
    }
#pragma unroll
    for (int off = 32; off; off >>= 1) {
        mm0 = fmaxf(mm0, __shfl_xor(mm0, off)); mm1 = fmaxf(mm1, __shfl_xor(mm1, off));
        mv0 = fmaxf(mv0, __shfl_xor(mv0, off)); mv1 = fmaxf(mv1, __shfl_xor(mv1, off));
    }
    float mem0 = (end > beg) ? lrelu(mm0 + erm0) : 0.f;
    float mem1 = (end > beg) ? lrelu(mm1 + erm1) : 0.f;
    float mev0 = (end > beg) ? lrelu(mv0 + erv0) : 0.f;
    float mev1 = (end > beg) ? lrelu(mv1 + erv1) : 0.f;

    const u16* ftp = tbl ? featv : featm;
    const int fidx = h * 16 + f;
    float accv = 0.f;
    float dm0 = 0.f, dm1 = 0.f, dv0 = 0.f, dv1 = 0.f;
    for (int base = beg; base < end; base += 64) {
        int i = base + lane;
        float wm0 = 0.f, wm1 = 0.f, wv0 = 0.f, wv1 = 0.f; int s = 0;
        if (i < end) {
            s = esrc[i];
            float2 em = *(const float2*)(elm + 2 * s);
            float2 ev = *(const float2*)(elv + 2 * s);
            wm0 = expf(lrelu(em.x + erm0) - mem0);
            wm1 = expf(lrelu(em.y + erm1) - mem1);
            wv0 = expf(lrelu(ev.x + erv0) - mev0);
            wv1 = expf(lrelu(ev.y + erv1) - mev1);
        }
        dm0 += wm0; dm1 += wm1; dv0 += wv0; dv1 += wv1;
        int cnt = min(64, end - base);
        for (int j = 0; j < cnt; ++j) {
            int sj = __shfl(s, j);
            float bm0 = __shfl(wm0, j);   // unconditional broadcasts (converged)
            float bm1 = __shfl(wm1, j);
            float bv0 = __shfl(wv0, j);
            float bv1 = __shfl(wv1, j);
            float wj = tbl ? (h ? bv1 : bv0) : (h ? bm1 : bm0);  // local select, safe
            accv += wj * bf2f(ftp[(size_t)sj * 32 + fidx]);
        }
    }
#pragma unroll
    for (int off = 32; off; off >>= 1) {
        dm0 += __shfl_xor(dm0, off); dm1 += __shfl_xor(dm1, off);
        dv0 += __shfl_xor(dv0, off); dv1 += __shfl_xor(dv1, off);
    }
    float den = tbl ? (h ? dv1 : dv0) : (h ? dm1 : dm0);
    float inv = (den > 0.f) ? 1.f / den : 0.f;
    float biasc = tbl ? bv[fidx] : bm[fidx];
    float outc = accv * inv + biasc;
    float hm = 0.5f * (outc + __shfl_xor(outc, 16));  // mean over the 2 heads (same tbl)
    float meanv = __shfl(hm, f);                      // tbl=0 lane
    float varp = __shfl(hm, 32 + f);                  // tbl=1 lane
    if (lane < 16) {
        float var = expf(varp);
        float z = meanv + sqrtf(var) * eps[(size_t)node * 16 + f];
        size_t base = (size_t)node * 16 + f;
        out[base] = z;
        out[(size_t)NNODES * 16 + base] = meanv;
        out[(size_t)2 * NNODES * 16 + base] = var;
    }
}

// ---------------- host ----------------
extern "C" void kernel_launch(void* const* d_in, const int* in_sizes, int n_in,
                              void* d_out, int out_size, void* d_ws, size_t ws_size,
                              hipStream_t stream) {
    const int N = NNODES, E = NEDGES;
    const float* x   = (const float*)d_in[0];
    const int* src   = (const int*)d_in[1];
    const int* dst   = (const int*)d_in[2];
    const float* W1  = (const float*)d_in[3];
    const float* al1 = (const float*)d_in[4];
    const float* ar1 = (const float*)d_in[5];
    const float* b1  = (const float*)d_in[6];
    const float* W2  = (const float*)d_in[7];
    const float* al2 = (const float*)d_in[8];
    const float* ar2 = (const float*)d_in[9];
    const float* b2  = (const float*)d_in[10];
    const float* Wm  = (const float*)d_in[11];
    const float* alm = (const float*)d_in[12];
    const float* arm = (const float*)d_in[13];
    const float* bm  = (const float*)d_in[14];
    const float* Wv  = (const float*)d_in[15];
    const float* alv = (const float*)d_in[16];
    const float* arv = (const float*)d_in[17];
    const float* bv  = (const float*)d_in[18];
    const float* eps = (const float*)d_in[19];
    float* out = (float*)d_out;

    char* ws = (char*)d_ws;
    size_t off = 0;
    auto take = [&](size_t bytes) { size_t r = off; off += (bytes + 255) & ~(size_t)255; return r; };
    int* counts   = (int*)(ws + take((size_t)N * 4));
    int* cursor   = (int*)(ws + take((size_t)N * 4));
    int* row_ptr  = (int*)(ws + take((size_t)(N + 1) * 4));
    int* bsums    = (int*)(ws + take(256 * 4));
    int* esrc     = (int*)(ws + take((size_t)E * 4));
    u16* W1t      = (u16*)(ws + take((size_t)128 * 1000 * 2));
    u16* W2t      = (u16*)(ws + take((size_t)256 * 128 * 2));
    u16* Wmt      = (u16*)(ws + take((size_t)32 * 128 * 2));
    u16* Wvt      = (u16*)(ws + take((size_t)32 * 128 * 2));
    float* el1    = (float*)(ws + take((size_t)N * 4));
    float* er1    = (float*)(ws + take((size_t)N * 4));
    float* el2    = (float*)(ws + take((size_t)N * 2 * 4));
    float* er2    = (float*)(ws + take((size_t)N * 2 * 4));
    float* elm    = (float*)(ws + take((size_t)N * 2 * 4));
    float* erm    = (float*)(ws + take((size_t)N * 2 * 4));
    float* elv    = (float*)(ws + take((size_t)N * 2 * 4));
    float* erv    = (float*)(ws + take((size_t)N * 2 * 4));
    u16* o_bf     = (u16*)(ws + take((size_t)N * 128 * 2));
    u16* o2_bf    = (u16*)(ws + take((size_t)N * 128 * 2));
    u16* R        = (u16*)(ws + take((size_t)N * 256 * 2));
    u16* feat1    = R;
    u16* feat2    = R;
    u16* featm    = R;
    u16* featv    = R + (size_t)N * 32;
    (void)ws_size; (void)n_in; (void)in_sizes; (void)out_size;

    const int nb = (N + 255) / 256;
    const int eb = (E + 255) / 256;
    const int wb = (N + 3) / 4;
    const int gb = (N + 63) / 64;

    // CSR build
    k_zero<<<dim3(nb), 256, 0, stream>>>(counts, N);
    k_zero<<<dim3(nb), 256, 0, stream>>>(cursor, N);
    k_count<<<dim3(eb), 256, 0, stream>>>(dst, counts, E);
    k_scan1<<<dim3(nb), 256, 0, stream>>>(counts, row_ptr, bsums, N);
    k_scan2<<<dim3(1), 256, 0, stream>>>(bsums, nb);
    k_scan3<<<dim3(nb), 256, 0, stream>>>(row_ptr, bsums, N, E);
    k_fill<<<dim3(eb), 256, 0, stream>>>(src, dst, row_ptr, cursor, esrc, E);

    // weight transposes (f32 -> bf16)
    k_transpose<<<dim3((1000 * 128 + 255) / 256), 256, 0, stream>>>(W1, W1t, 1000, 128);
    k_transpose<<<dim3((128 * 256 + 255) / 256), 256, 0, stream>>>(W2, W2t, 128, 256);
    k_transpose<<<dim3((128 * 32 + 255) / 256), 256, 0, stream>>>(Wm, Wmt, 128, 32);
    k_transpose<<<dim3((128 * 32 + 255) / 256), 256, 0, stream>>>(Wv, Wvt, 128, 32);

    // layer 1 (A is f32)
    k_gemm_tiled<float><<<dim3(gb, 1), 256, 0, stream>>>(x, W1t, feat1, N, 128, 1000);
    k_eler1<<<dim3(wb), 256, 0, stream>>>(feat1, al1, ar1, el1, er1, N);
    k_agg1<<<dim3(wb), 256, 0, stream>>>(row_ptr, esrc, feat1, el1, er1, b1, o_bf, N);

    // layer 2
    k_gemm_tiled<u16><<<dim3(gb, 2), 256, 0, stream>>>(o_bf, W2t, feat2, N, 256, 128);
    k_eler2<<<dim3(wb), 256, 0, stream>>>(feat2, al2, ar2, el2, er2, N);
    k_agg2<<<dim3(wb), 256, 0, stream>>>(row_ptr, esrc, feat2, el2, er2, b2, o_bf, o2_bf, N);

    // mean/var layers
    k_gemm<2><<<dim3(N / 16, 1), 64, 0, stream>>>(o2_bf, Wmt, featm, N, 32, 128);
    k_gemm<2><<<dim3(N / 16, 1), 64, 0, stream>>>(o2_bf, Wvt, featv, N, 32, 128);
    k_elermv<<<dim3(wb), 256, 0, stream>>>(featm, featv, alm, arm, alv, arv, elm, erm, elv, erv, N);
    k_aggmv<<<dim3(wb), 256, 0, stream>>>(row_ptr, esrc, featm, featv, elm, erm, elv, erv,
                                          bm, bv, eps, out, N);
}